// Round 7
// baseline (1361.217 us; speedup 1.0000x reference)
//
#include <hip/hip_runtime.h>

// ---------------- constants ----------------
#define M_TOK 18464      // 32*577 tokens
#define TSEQ  577
#define NBATCH 32
#define NH    16
#define HD    64
#define DIMM  1024
#define HIDD  4096
#define NTM   73         // ceil(18464/256)

typedef __attribute__((ext_vector_type(4))) float f32x4;
typedef __attribute__((ext_vector_type(8))) short bf8;   // 8 bf16 (MFMA A/B frag)
typedef __attribute__((ext_vector_type(8))) short s8v;
typedef __attribute__((ext_vector_type(4))) short s4v;

__device__ __forceinline__ short f2bf(float f) {
  union { float f; unsigned u; } c; c.f = f;
  unsigned u = c.u;
  unsigned r = (u + 0x7fffu + ((u >> 16) & 1u)) >> 16;  // RNE
  return (short)r;
}

// async global->LDS, 16B per lane; dest = wave-uniform base + lane*16
__device__ __forceinline__ void gld_lds16(const short* g, short* l) {
  __builtin_amdgcn_global_load_lds(
      (const __attribute__((address_space(1))) unsigned int*)g,
      (__attribute__((address_space(3))) unsigned int*)l, 16, 0, 0);
}

#define MFMA16(a, b, c) __builtin_amdgcn_mfma_f32_16x16x32_bf16(a, b, c, 0, 0, 0)

// stage 64 rows x 64 cols (bf16) of G into LDS, chunk^(row&7) swizzled source,
// linear LDS dest. One gld_lds instruction per thread (512 threads).
__device__ __forceinline__ void stage64(const short* __restrict__ G, int rg0, int ld,
                                        int rmax, int kcol, short* lbase, int t) {
  int rl = t >> 3, c = t & 7;
  int cs = c ^ (rl & 7);
  int rg = rg0 + rl;
  if (rg > rmax) rg = rmax;
  gld_lds16(G + (size_t)rg * ld + kcol + cs * 8, lbase + (t & 448) * 8);
}

// ---------------- weight convert + transpose: W[K][N] f32 -> WT[N][K] bf16 ----------------
__global__ __launch_bounds__(256) void conv_t_kernel(const float* __restrict__ W,
                                                     short* __restrict__ WT,
                                                     int K, int N) {
  __shared__ short tile[32][33];
  int bx = blockIdx.x;  // n tile
  int by = blockIdx.y;  // k tile
  int t = threadIdx.x;
  int c = t & 31, r = t >> 5;  // 32 cols x 8 rows
#pragma unroll
  for (int rr = r; rr < 32; rr += 8)
    tile[rr][c] = f2bf(W[(size_t)(by * 32 + rr) * N + bx * 32 + c]);
  __syncthreads();
#pragma unroll
  for (int rr = r; rr < 32; rr += 8)
    WT[(size_t)(bx * 32 + rr) * K + by * 32 + c] = tile[c][rr];
}

// ---------------- layernorm: f32 [M][1024] -> bf16 [M][1024] ----------------
__global__ __launch_bounds__(256) void ln_kernel(const float* __restrict__ x,
                                                 const float* __restrict__ g,
                                                 const float* __restrict__ b,
                                                 short* __restrict__ out) {
  __shared__ float red[4];
  int row = blockIdx.x;
  int t = threadIdx.x, w = t >> 6, l = t & 63;
  const float4* xr = (const float4*)(x + (size_t)row * DIMM);
  float4 v = xr[t];
  float s1 = v.x + v.y + v.z + v.w;
#pragma unroll
  for (int m = 1; m < 64; m <<= 1) s1 += __shfl_xor(s1, m);
  if (l == 0) red[w] = s1;
  __syncthreads();
  float mu = (red[0] + red[1] + red[2] + red[3]) * (1.0f / 1024.0f);
  float dx = v.x - mu, dy = v.y - mu, dz = v.z - mu, dw = v.w - mu;
  float s2 = dx * dx + dy * dy + dz * dz + dw * dw;
#pragma unroll
  for (int m = 1; m < 64; m <<= 1) s2 += __shfl_xor(s2, m);
  __syncthreads();
  if (l == 0) red[w] = s2;
  __syncthreads();
  float var = (red[0] + red[1] + red[2] + red[3]) * (1.0f / 1024.0f);
  float rs = rsqrtf(var + 1e-6f);
  const float4* g4 = (const float4*)g;
  const float4* b4 = (const float4*)b;
  float4 gv = g4[t], bv = b4[t];
  s4v o;
  o[0] = f2bf(dx * rs * gv.x + bv.x);
  o[1] = f2bf(dy * rs * gv.y + bv.y);
  o[2] = f2bf(dz * rs * gv.z + bv.z);
  o[3] = f2bf(dw * rs * gv.w + bv.w);
  *(s4v*)(out + (size_t)row * DIMM + t * 4) = o;
}

// ---------------- GEMM 256x256x64, double-buffered, counted vmcnt(8) ----------------
// C[M][N] = A[M][K](bf16, lda) @ BT[N][K](bf16, ldb)^T + bias
// EPI 0: bf16 = C+bias  | EPI 1: f32 = C+bias+res | EPI 2: bf16 = gelu(C+bias) | EPI 3: f32 += C
// 8 waves = 2(m) x 4(n); per-wave 128x64 out = acc[8][4]. 64 MFMA/wave per K-tile
// between ONE barrier pair. LDS 2 x (A 256x64 + B 256x64) = 128 KB.
// Pipeline: gate vmcnt(8) [kt landed, kt+1 in flight]; compute kt (no inner barriers);
// lgkmcnt(0)+barrier [all reads done]; stage kt+2 into the vacated buffer.
template <int EPI>
__global__ __launch_bounds__(512, 1) void gemm256_kernel(const short* __restrict__ A,
                                                         const short* __restrict__ BT,
                                                         const float* __restrict__ bias,
                                                         const float* res, short* outh,
                                                         float* outf, int M, int K, int N,
                                                         int lda, int ldb, int ntn) {
  __shared__ short lA[2 * 256 * 64];
  __shared__ short lB[2 * 256 * 64];
  // bijective XCD swizzle (works for any grid size)
  int nwg = gridDim.x;
  int q = nwg >> 3, r = nwg & 7;
  int xcd = blockIdx.x & 7, idx = blockIdx.x >> 3;
  int bid = (xcd < r ? xcd * (q + 1) : r * (q + 1) + (xcd - r) * q) + idx;
  int tm = bid / ntn, tn = bid % ntn;
  int m0 = tm * 256, n0 = tn * 256;
  int t = threadIdx.x, l = t & 63;
  int w = t >> 6, wm = w >> 2, wn = w & 3;  // 2M x 4N
  f32x4 acc[8][4] = {};
  const int NKT = K >> 6;

  // prologue: kt0 -> buf0 (8 loads/thread), kt1 -> buf1 (8 loads/thread)
#pragma unroll
  for (int u = 0; u < 4; ++u) stage64(A, m0 + u * 64, lda, M - 1, 0, &lA[u * 4096], t);
#pragma unroll
  for (int u = 0; u < 4; ++u) stage64(BT, n0 + u * 64, ldb, N - 1, 0, &lB[u * 4096], t);
#pragma unroll
  for (int u = 0; u < 4; ++u) stage64(A, m0 + u * 64, lda, M - 1, 64, &lA[16384 + u * 4096], t);
#pragma unroll
  for (int u = 0; u < 4; ++u) stage64(BT, n0 + u * 64, ldb, N - 1, 64, &lB[16384 + u * 4096], t);

  for (int it = 0; it < NKT; ++it) {
    // gate: k-tile 'it' landed; 'it+1''s 8 loads may stay in flight
    if (it == NKT - 1) {
      asm volatile("s_waitcnt vmcnt(0)" ::: "memory");
    } else {
      asm volatile("s_waitcnt vmcnt(8)" ::: "memory");
    }
    __builtin_amdgcn_s_barrier();
    __builtin_amdgcn_sched_barrier(0);
    const short* cA = &lA[(it & 1) * 16384];
    const short* cB = &lB[(it & 1) * 16384];

    // B fragments for the whole K-tile (8 x ds_read_b128, conflict-free)
    bf8 bfr[4][2];
#pragma unroll
    for (int n = 0; n < 4; ++n)
#pragma unroll
      for (int ks = 0; ks < 2; ++ks) {
        int rr = wn * 64 + n * 16 + (l & 15);
        int g = ks * 4 + (l >> 4);
        bfr[n][ks] = *(const bf8*)&cB[rr * 64 + (g ^ (rr & 7)) * 8];
      }
    // 4 phases x {4 A-reads, 16 MFMA}; no barriers inside (read-only LDS)
#pragma unroll
    for (int ph = 0; ph < 4; ++ph) {
      bf8 af[2][2];
#pragma unroll
      for (int i = 0; i < 2; ++i)
#pragma unroll
        for (int ks = 0; ks < 2; ++ks) {
          int rr = wm * 128 + (ph * 2 + i) * 16 + (l & 15);
          int g = ks * 4 + (l >> 4);
          af[i][ks] = *(const bf8*)&cA[rr * 64 + (g ^ (rr & 7)) * 8];
        }
      __builtin_amdgcn_s_setprio(1);
#pragma unroll
      for (int i = 0; i < 2; ++i)
#pragma unroll
        for (int n = 0; n < 4; ++n)
#pragma unroll
          for (int ks = 0; ks < 2; ++ks)
            acc[ph * 2 + i][n] = MFMA16(af[i][ks], bfr[n][ks], acc[ph * 2 + i][n]);
      __builtin_amdgcn_s_setprio(0);
    }
    // all this wave's LDS reads retired, then all waves -> safe to overwrite buf
    asm volatile("s_waitcnt lgkmcnt(0)" ::: "memory");
    __builtin_amdgcn_sched_barrier(0);
    __builtin_amdgcn_s_barrier();
    __builtin_amdgcn_sched_barrier(0);
    int ktp = it + 2;
    if (ktp < NKT) {
      int kcol = ktp << 6;
      short* pA = &lA[(it & 1) * 16384];
      short* pB = &lB[(it & 1) * 16384];
#pragma unroll
      for (int u = 0; u < 4; ++u) stage64(A, m0 + u * 64, lda, M - 1, kcol, pA + u * 4096, t);
#pragma unroll
      for (int u = 0; u < 4; ++u) stage64(BT, n0 + u * 64, ldb, N - 1, kcol, pB + u * 4096, t);
    }
  }

  // epilogue: C/D layout col=lane&15, row=4*(lane>>4)+reg
#pragma unroll
  for (int jf = 0; jf < 4; ++jf) {
    int col = n0 + wn * 64 + jf * 16 + (l & 15);
    float bz = (EPI == 3) ? 0.f : bias[col];
#pragma unroll
    for (int ifr = 0; ifr < 8; ++ifr) {
      int rbase = m0 + wm * 128 + ifr * 16 + (l >> 4) * 4;
#pragma unroll
      for (int qq = 0; qq < 4; ++qq) {
        int row = rbase + qq;
        if (row < M) {
          float v = acc[ifr][jf][qq] + bz;
          size_t idxo = (size_t)row * N + col;
          if constexpr (EPI == 0) {
            outh[idxo] = f2bf(v);
          } else if constexpr (EPI == 1) {
            outf[idxo] = v + res[idxo];
          } else if constexpr (EPI == 2) {
            float gl = 0.5f * v * (1.0f + erff(v * 0.70710678118f));
            outh[idxo] = f2bf(gl);
          } else {
            outf[idxo] += v;
          }
        }
      }
    }
  }
}

// ---------------- flash attention (unchanged from R5 pass) ----------------
__global__ __launch_bounds__(256, 4) void attn_kernel(const short* __restrict__ qkv,
                                                      short* __restrict__ aout) {
  __shared__ short lK[64 * 64];
  __shared__ short lV[64 * 64];
  __shared__ short lP[4 * 16 * 64];
  int bh = blockIdx.x;
  int qt = blockIdx.y;
  int b = bh >> 4, h = bh & 15;
  int t = threadIdx.x, w = t >> 6, l = t & 63;
  int m0 = qt * 64;
  const size_t tokbase = (size_t)b * TSEQ;
  unsigned lvb = (unsigned)(uintptr_t)&lV[0];

  int tq0 = m0 + w * 16 + (l & 15); if (tq0 > TSEQ - 1) tq0 = TSEQ - 1;
  const short* qrow = qkv + (tokbase + tq0) * 3072 + h * 64;
  bf8 qf[2];
  qf[0] = *(const bf8*)(qrow + (l >> 4) * 8);
  qf[1] = *(const bf8*)(qrow + 32 + (l >> 4) * 8);

  float m_run[4], l_run[4], p[4][4];
  f32x4 o_acc[4] = {};
#pragma unroll
  for (int q = 0; q < 4; q++) { m_run[q] = -1e30f; l_run[q] = 0.f; }

  for (int kt = 0; kt < 10; ++kt) {
    __syncthreads();
#pragma unroll
    for (int i = 0; i < 2; i++) {
      int L = i * 256 + t;
      int key = L >> 3;
      int cd = (L & 7) ^ (key & 7);
      int tok = kt * 64 + key; if (tok > TSEQ - 1) tok = TSEQ - 1;
      gld_lds16(qkv + (tokbase + tok) * 3072 + 1024 + h * 64 + cd * 8,
                &lK[(i * 256 + w * 64) * 8]);
    }
#pragma unroll
    for (int i = 0; i < 2; i++) {
      int L = i * 256 + t;
      int k = (L >> 5) * 4 + ((L >> 1) & 3);
      int c = ((L >> 3) & 3) * 2 + (L & 1);
      int tok = kt * 64 + k; if (tok > TSEQ - 1) tok = TSEQ - 1;
      gld_lds16(qkv + (tokbase + tok) * 3072 + 2048 + h * 64 + c * 8,
                &lV[(i * 256 + w * 64) * 8]);
    }
    __syncthreads();

    f32x4 s[4];
    __builtin_amdgcn_s_setprio(1);
#pragma unroll
    for (int nf = 0; nf < 4; ++nf) {
      f32x4 a = {};
#pragma unroll
      for (int ks = 0; ks < 2; ++ks) {
        int keyrow = nf * 16 + (l & 15);
        int cp = (ks * 4 + (l >> 4)) ^ (keyrow & 7);
        bf8 kf = *(const bf8*)&lK[keyrow * 64 + cp * 8];
        a = MFMA16(qf[ks], kf, a);
      }
      int key = kt * 64 + nf * 16 + (l & 15);
      bool valid = key < TSEQ;
#pragma unroll
      for (int q = 0; q < 4; q++) s[nf][q] = valid ? a[q] * 0.125f : -1e30f;
    }
    __builtin_amdgcn_s_setprio(0);

#pragma unroll
    for (int q = 0; q < 4; q++) {
      float rm = fmaxf(fmaxf(s[0][q], s[1][q]), fmaxf(s[2][q], s[3][q]));
#pragma unroll
      for (int mm = 1; mm < 16; mm <<= 1) rm = fmaxf(rm, __shfl_xor(rm, mm));
      float mnew = fmaxf(m_run[q], rm);
      float corr = __expf(m_run[q] - mnew);
      m_run[q] = mnew;
      float rs = 0.f;
#pragma unroll
      for (int nf = 0; nf < 4; nf++) {
        float pv = __expf(s[nf][q] - mnew);
        p[nf][q] = pv;
        rs += pv;
      }
#pragma unroll
      for (int mm = 1; mm < 16; mm <<= 1) rs += __shfl_xor(rs, mm);
      l_run[q] = l_run[q] * corr + rs;
#pragma unroll
      for (int df = 0; df < 4; df++) o_acc[df][q] *= corr;
    }
#pragma unroll
    for (int nf = 0; nf < 4; nf++)
#pragma unroll
      for (int q = 0; q < 4; q++) {
        int qr = (l >> 4) * 4 + q;
        int key = nf * 16 + (l & 15);
        int cp = (key >> 3) ^ (qr & 7);
        lP[w * 1024 + qr * 64 + cp * 8 + (key & 7)] = f2bf(p[nf][q]);
      }
    __syncthreads();

#pragma unroll
    for (int ks = 0; ks < 2; ++ks) {
      int qr = l & 15;
      int cp = (ks * 4 + (l >> 4)) ^ (qr & 7);
      bf8 pf = *(const bf8*)&lP[w * 1024 + qr * 64 + cp * 8];
      unsigned kq0 = (unsigned)(ks * 8 + (l >> 4) * 2);
      unsigned abase = lvb + kq0 * 512u + (unsigned)(l & 15) * 8u;
      s4v ra0, ra1, rb0, rb1, rc0, rc1, rd0, rd1;
      asm volatile("ds_read_b64_tr_b16 %0, %1" : "=v"(ra0) : "v"(abase));
      asm volatile("ds_read_b64_tr_b16 %0, %1" : "=v"(ra1) : "v"(abase + 512u));
      asm volatile("ds_read_b64_tr_b16 %0, %1" : "=v"(rb0) : "v"(abase + 128u));
      asm volatile("ds_read_b64_tr_b16 %0, %1" : "=v"(rb1) : "v"(abase + 640u));
      asm volatile("ds_read_b64_tr_b16 %0, %1" : "=v"(rc0) : "v"(abase + 256u));
      asm volatile("ds_read_b64_tr_b16 %0, %1" : "=v"(rc1) : "v"(abase + 768u));
      asm volatile("ds_read_b64_tr_b16 %0, %1" : "=v"(rd0) : "v"(abase + 384u));
      asm volatile("ds_read_b64_tr_b16 %0, %1" : "=v"(rd1) : "v"(abase + 896u));
      asm volatile("s_waitcnt lgkmcnt(0)" ::: "memory");
      __builtin_amdgcn_sched_barrier(0);
      bf8 vfa = __builtin_shufflevector(ra0, ra1, 0, 1, 2, 3, 4, 5, 6, 7);
      bf8 vfb = __builtin_shufflevector(rb0, rb1, 0, 1, 2, 3, 4, 5, 6, 7);
      bf8 vfc = __builtin_shufflevector(rc0, rc1, 0, 1, 2, 3, 4, 5, 6, 7);
      bf8 vfd = __builtin_shufflevector(rd0, rd1, 0, 1, 2, 3, 4, 5, 6, 7);
      __builtin_amdgcn_s_setprio(1);
      o_acc[0] = MFMA16(pf, vfa, o_acc[0]);
      o_acc[1] = MFMA16(pf, vfb, o_acc[1]);
      o_acc[2] = MFMA16(pf, vfc, o_acc[2]);
      o_acc[3] = MFMA16(pf, vfd, o_acc[3]);
      __builtin_amdgcn_s_setprio(0);
    }
  }
#pragma unroll
  for (int df = 0; df < 4; df++) {
#pragma unroll
    for (int q = 0; q < 4; q++) {
      int tq = m0 + w * 16 + (l >> 4) * 4 + q;
      if (tq < TSEQ) {
        float val = o_acc[df][q] / l_run[q];
        aout[(tokbase + tq) * DIMM + h * 64 + df * 16 + (l & 15)] = f2bf(val);
      }
    }
  }
}

// ---------------- launch ----------------
extern "C" void kernel_launch(void* const* d_in, const int* in_sizes, int n_in,
                              void* d_out, int out_size, void* d_ws, size_t ws_size,
                              hipStream_t stream) {
  const float* x      = (const float*)d_in[0];
  const float* ln1_g  = (const float*)d_in[1];
  const float* ln1_b  = (const float*)d_in[2];
  const float* qkv_w  = (const float*)d_in[3];
  const float* qkv_b  = (const float*)d_in[4];
  const float* proj_w = (const float*)d_in[5];
  const float* proj_b = (const float*)d_in[6];
  const float* ln2_g  = (const float*)d_in[7];
  const float* ln2_b  = (const float*)d_in[8];
  const float* fc1_w  = (const float*)d_in[9];
  const float* fc1_b  = (const float*)d_in[10];
  const float* fc2_w  = (const float*)d_in[11];
  const float* fc2_b  = (const float*)d_in[12];
  float* out = (float*)d_out;

  const size_t REQ = (size_t)(12582912 + (size_t)M_TOK * 1024 + (size_t)M_TOK * 3072) * 2;
  if (ws_size < REQ) return;

  short* w_qkv  = (short*)d_ws;                      // [3072][1024]
  short* w_proj = w_qkv + (size_t)3072 * 1024;       // [1024][1024]
  short* w_fc1  = w_proj + (size_t)1024 * 1024;      // [4096][1024]
  short* w_fc2  = w_fc1 + (size_t)4096 * 1024;       // [1024][4096]
  short* bufA   = w_fc2 + (size_t)1024 * 4096;       // [M][1024]
  short* bufB   = bufA + (size_t)M_TOK * 1024;       // [M][3072]

  dim3 blk(256);
  dim3 blk512(512);
  conv_t_kernel<<<dim3(3072 / 32, 1024 / 32), blk, 0, stream>>>(qkv_w, w_qkv, 1024, 3072);
  conv_t_kernel<<<dim3(1024 / 32, 1024 / 32), blk, 0, stream>>>(proj_w, w_proj, 1024, 1024);
  conv_t_kernel<<<dim3(4096 / 32, 1024 / 32), blk, 0, stream>>>(fc1_w, w_fc1, 1024, 4096);
  conv_t_kernel<<<dim3(1024 / 32, 4096 / 32), blk, 0, stream>>>(fc2_w, w_fc2, 4096, 1024);
  // LN1: x -> bufA
  ln_kernel<<<M_TOK, blk, 0, stream>>>(x, ln1_g, ln1_b, bufA);
  // QKV: bufA @ w_qkv^T -> bufB   (grid 73*12 = 876)
  gemm256_kernel<0><<<NTM * 12, blk512, 0, stream>>>(bufA, w_qkv, qkv_b, nullptr, bufB,
                                                     nullptr, M_TOK, 1024, 3072, 1024, 1024, 12);
  // attention: bufB -> bufA
  attn_kernel<<<dim3(NBATCH * NH, 10), blk, 0, stream>>>(bufB, bufA);
  // proj + residual(x) -> out (x1)   (grid 292)
  gemm256_kernel<1><<<NTM * 4, blk512, 0, stream>>>(bufA, w_proj, proj_b, x, nullptr, out,
                                                    M_TOK, 1024, 1024, 1024, 1024, 4);
  // LN2 on x1 -> bufA
  ln_kernel<<<M_TOK, blk, 0, stream>>>(out, ln2_g, ln2_b, bufA);
  // FFN in 2 hidden-dim chunks of 2048
  for (int c = 0; c < 2; ++c) {
    // FC1 chunk + GELU: bufA @ w_fc1[c*2048:+2048]^T -> bufB [M][2048]  (grid 584)
    gemm256_kernel<2><<<NTM * 8, blk512, 0, stream>>>(bufA, w_fc1 + (size_t)c * 2048 * 1024,
                                                      fc1_b + c * 2048, nullptr, bufB, nullptr,
                                                      M_TOK, 1024, 2048, 1024, 1024, 8);
    // FC2 chunk: out (+)= bufB @ w_fc2[:, c*2048:+2048]^T  (grid 292)
    if (c == 0) {
      gemm256_kernel<1><<<NTM * 4, blk512, 0, stream>>>(bufB, w_fc2 + (size_t)c * 2048, fc2_b,
                                                        out, nullptr, out, M_TOK, 2048, 1024,
                                                        2048, 4096, 4);
    } else {
      gemm256_kernel<3><<<NTM * 4, blk512, 0, stream>>>(bufB, w_fc2 + (size_t)c * 2048, fc2_b,
                                                        out, nullptr, out, M_TOK, 2048, 1024,
                                                        2048, 4096, 4);
    }
  }
}

// Round 8
// 1199.616 us; speedup vs baseline: 1.1347x; 1.1347x over previous
//
#include <hip/hip_runtime.h>

// ---------------- constants ----------------
#define M_TOK 18464      // 32*577 tokens
#define TSEQ  577
#define NBATCH 32
#define NH    16
#define HD    64
#define DIMM  1024
#define HIDD  4096
#define NTMK  145        // ceil(18464/128)

typedef __attribute__((ext_vector_type(4))) float f32x4;
typedef __attribute__((ext_vector_type(8))) short bf8;   // 8 bf16 (MFMA A/B frag)
typedef __attribute__((ext_vector_type(8))) short s8v;
typedef __attribute__((ext_vector_type(4))) short s4v;

__device__ __forceinline__ short f2bf(float f) {
  union { float f; unsigned u; } c; c.f = f;
  unsigned u = c.u;
  unsigned r = (u + 0x7fffu + ((u >> 16) & 1u)) >> 16;  // RNE
  return (short)r;
}

// async global->LDS, 16B per lane; dest = wave-uniform base + lane*16
__device__ __forceinline__ void gld_lds16(const short* g, short* l) {
  __builtin_amdgcn_global_load_lds(
      (const __attribute__((address_space(1))) unsigned int*)g,
      (__attribute__((address_space(3))) unsigned int*)l, 16, 0, 0);
}

#define MFMA16(a, b, c) __builtin_amdgcn_mfma_f32_16x16x32_bf16(a, b, c, 0, 0, 0)

// ---------------- weight convert + transpose: W[K][N] f32 -> WT[N][K] bf16 ----------------
__global__ __launch_bounds__(256) void conv_t_kernel(const float* __restrict__ W,
                                                     short* __restrict__ WT,
                                                     int K, int N) {
  __shared__ short tile[32][33];
  int bx = blockIdx.x;  // n tile
  int by = blockIdx.y;  // k tile
  int t = threadIdx.x;
  int c = t & 31, r = t >> 5;  // 32 cols x 8 rows
#pragma unroll
  for (int rr = r; rr < 32; rr += 8)
    tile[rr][c] = f2bf(W[(size_t)(by * 32 + rr) * N + bx * 32 + c]);
  __syncthreads();
#pragma unroll
  for (int rr = r; rr < 32; rr += 8)
    WT[(size_t)(bx * 32 + rr) * K + by * 32 + c] = tile[c][rr];
}

// ---------------- layernorm: f32 [M][1024] -> bf16 [M][1024] ----------------
__global__ __launch_bounds__(256) void ln_kernel(const float* __restrict__ x,
                                                 const float* __restrict__ g,
                                                 const float* __restrict__ b,
                                                 short* __restrict__ out) {
  __shared__ float red[4];
  int row = blockIdx.x;
  int t = threadIdx.x, w = t >> 6, l = t & 63;
  const float4* xr = (const float4*)(x + (size_t)row * DIMM);
  float4 v = xr[t];
  float s1 = v.x + v.y + v.z + v.w;
#pragma unroll
  for (int m = 1; m < 64; m <<= 1) s1 += __shfl_xor(s1, m);
  if (l == 0) red[w] = s1;
  __syncthreads();
  float mu = (red[0] + red[1] + red[2] + red[3]) * (1.0f / 1024.0f);
  float dx = v.x - mu, dy = v.y - mu, dz = v.z - mu, dw = v.w - mu;
  float s2 = dx * dx + dy * dy + dz * dz + dw * dw;
#pragma unroll
  for (int m = 1; m < 64; m <<= 1) s2 += __shfl_xor(s2, m);
  __syncthreads();
  if (l == 0) red[w] = s2;
  __syncthreads();
  float var = (red[0] + red[1] + red[2] + red[3]) * (1.0f / 1024.0f);
  float rs = rsqrtf(var + 1e-6f);
  const float4* g4 = (const float4*)g;
  const float4* b4 = (const float4*)b;
  float4 gv = g4[t], bv = b4[t];
  s4v o;
  o[0] = f2bf(dx * rs * gv.x + bv.x);
  o[1] = f2bf(dy * rs * gv.y + bv.y);
  o[2] = f2bf(dz * rs * gv.z + bv.z);
  o[3] = f2bf(dw * rs * gv.w + bv.w);
  *(s4v*)(out + (size_t)row * DIMM + t * 4) = o;
}

// ---------------- GEMM 128x128x64, 2-phase counted schedule ----------------
// C[M][N] = A[M][K](bf16, lda) @ BT[N][K](bf16, ldb)^T + bias
// EPI 0: bf16 = C+bias | EPI 1: f32 = C+bias+res | EPI 2: bf16 = gelu(C+bias) | EPI 3: f32 += C
// 4 waves 2x2, per-wave 64x64. Double-buffered 64KB LDS -> 2 blocks/CU.
// Per K-tile: STAGE(it+1) -> compute(it) -> vmcnt(0)+barrier. Load latency hides
// under ~1500cyc of compute instead of being drained right after issue (R5 flaw).
// Staging uses chunk^(row&7) pre-swizzled source (zero bank conflicts, proven R6/R7).
template <int EPI>
__global__ __launch_bounds__(256, 2) void gemm_kernel(const short* __restrict__ A,
                                                      const short* __restrict__ BT,
                                                      const float* __restrict__ bias,
                                                      const float* res, short* outh,
                                                      float* outf, int M, int K, int N,
                                                      int lda, int ldb, int ntn) {
  __shared__ short lA[2 * 128 * 64];
  __shared__ short lB[2 * 128 * 64];
  // bijective XCD swizzle (any grid size)
  int nwg = gridDim.x;
  int qd = nwg >> 3, rd = nwg & 7;
  int xcd = blockIdx.x & 7, ix = blockIdx.x >> 3;
  int bid = (xcd < rd ? xcd * (qd + 1) : rd * (qd + 1) + (xcd - rd) * qd) + ix;
  int tm = bid / ntn, tn = bid % ntn;
  int m0 = tm * 128, n0 = tn * 128;
  int t = threadIdx.x, l = t & 63;
  int w = t >> 6, wm = w >> 1, wn = w & 1;
  f32x4 acc[4][4] = {};
  const int NKT = K >> 6;

  // stage one 128x64 A-tile + 128x64 B-tile (8 gld_lds16/thread)
  auto STAGE = [&](int kt, int bs) {
    int kcol = kt << 6;
#pragma unroll
    for (int i = 0; i < 4; i++) {
      int L = i * 256 + t;
      int row = L >> 3, cs = (L & 7) ^ (row & 7);
      int mg = m0 + row;
      if (mg > M - 1) mg = M - 1;
      gld_lds16(A + (size_t)mg * lda + kcol + cs * 8,
                &lA[(bs * 1024 + i * 256 + (t & 448)) * 8]);
    }
#pragma unroll
    for (int i = 0; i < 4; i++) {
      int L = i * 256 + t;
      int row = L >> 3, cs = (L & 7) ^ (row & 7);
      gld_lds16(BT + (size_t)(n0 + row) * ldb + kcol + cs * 8,
                &lB[(bs * 1024 + i * 256 + (t & 448)) * 8]);
    }
  };

  STAGE(0, 0);
  asm volatile("s_waitcnt vmcnt(0)" ::: "memory");
  __builtin_amdgcn_s_barrier();
  __builtin_amdgcn_sched_barrier(0);
  for (int it = 0; it < NKT; ++it) {
    int bs = it & 1;
    if (it + 1 < NKT) STAGE(it + 1, bs ^ 1);  // issue early; lands under compute
    const short* cA = &lA[bs * 8192];
    const short* cB = &lB[bs * 8192];
#pragma unroll
    for (int ks = 0; ks < 2; ++ks) {
      bf8 af[4], bfr[4];
      int g = ks * 4 + (l >> 4);
#pragma unroll
      for (int i = 0; i < 4; i++) {
        int r = wm * 64 + i * 16 + (l & 15);
        af[i] = *(const bf8*)&cA[r * 64 + (g ^ (r & 7)) * 8];
      }
#pragma unroll
      for (int j = 0; j < 4; j++) {
        int r = wn * 64 + j * 16 + (l & 15);
        bfr[j] = *(const bf8*)&cB[r * 64 + (g ^ (r & 7)) * 8];
      }
      __builtin_amdgcn_s_setprio(1);
#pragma unroll
      for (int i = 0; i < 4; i++)
#pragma unroll
        for (int j = 0; j < 4; j++) acc[i][j] = MFMA16(af[i], bfr[j], acc[i][j]);
      __builtin_amdgcn_s_setprio(0);
    }
    // next tile's loads have had the whole compute phase to land -> cheap drain
    asm volatile("s_waitcnt vmcnt(0)" ::: "memory");
    __builtin_amdgcn_s_barrier();
    __builtin_amdgcn_sched_barrier(0);
  }

  // epilogue: C/D layout col=lane&15, row=4*(lane>>4)+reg
#pragma unroll
  for (int jf = 0; jf < 4; ++jf) {
    int col = n0 + wn * 64 + jf * 16 + (l & 15);
    float bz = (EPI == 3) ? 0.f : bias[col];
#pragma unroll
    for (int ifr = 0; ifr < 4; ++ifr) {
      int rbase = m0 + wm * 64 + ifr * 16 + (l >> 4) * 4;
#pragma unroll
      for (int qv = 0; qv < 4; ++qv) {
        int row = rbase + qv;
        if (row < M) {
          float v = acc[ifr][jf][qv] + bz;
          size_t idx = (size_t)row * N + col;
          if constexpr (EPI == 0) {
            outh[idx] = f2bf(v);
          } else if constexpr (EPI == 1) {
            outf[idx] = v + res[idx];
          } else if constexpr (EPI == 2) {
            float gl = 0.5f * v * (1.0f + erff(v * 0.70710678118f));
            outh[idx] = f2bf(gl);
          } else {
            outf[idx] += v;
          }
        }
      }
    }
  }
}

// ---------------- flash attention (unchanged from R5 pass) ----------------
__global__ __launch_bounds__(256, 4) void attn_kernel(const short* __restrict__ qkv,
                                                      short* __restrict__ aout) {
  __shared__ short lK[64 * 64];
  __shared__ short lV[64 * 64];
  __shared__ short lP[4 * 16 * 64];
  int bh = blockIdx.x;
  int qt = blockIdx.y;
  int b = bh >> 4, h = bh & 15;
  int t = threadIdx.x, w = t >> 6, l = t & 63;
  int m0 = qt * 64;
  const size_t tokbase = (size_t)b * TSEQ;
  unsigned lvb = (unsigned)(uintptr_t)&lV[0];

  int tq0 = m0 + w * 16 + (l & 15); if (tq0 > TSEQ - 1) tq0 = TSEQ - 1;
  const short* qrow = qkv + (tokbase + tq0) * 3072 + h * 64;
  bf8 qf[2];
  qf[0] = *(const bf8*)(qrow + (l >> 4) * 8);
  qf[1] = *(const bf8*)(qrow + 32 + (l >> 4) * 8);

  float m_run[4], l_run[4], p[4][4];
  f32x4 o_acc[4] = {};
#pragma unroll
  for (int q = 0; q < 4; q++) { m_run[q] = -1e30f; l_run[q] = 0.f; }

  for (int kt = 0; kt < 10; ++kt) {
    __syncthreads();
#pragma unroll
    for (int i = 0; i < 2; i++) {
      int L = i * 256 + t;
      int key = L >> 3;
      int cd = (L & 7) ^ (key & 7);
      int tok = kt * 64 + key; if (tok > TSEQ - 1) tok = TSEQ - 1;
      gld_lds16(qkv + (tokbase + tok) * 3072 + 1024 + h * 64 + cd * 8,
                &lK[(i * 256 + w * 64) * 8]);
    }
#pragma unroll
    for (int i = 0; i < 2; i++) {
      int L = i * 256 + t;
      int k = (L >> 5) * 4 + ((L >> 1) & 3);
      int c = ((L >> 3) & 3) * 2 + (L & 1);
      int tok = kt * 64 + k; if (tok > TSEQ - 1) tok = TSEQ - 1;
      gld_lds16(qkv + (tokbase + tok) * 3072 + 2048 + h * 64 + c * 8,
                &lV[(i * 256 + w * 64) * 8]);
    }
    __syncthreads();

    f32x4 s[4];
    __builtin_amdgcn_s_setprio(1);
#pragma unroll
    for (int nf = 0; nf < 4; ++nf) {
      f32x4 a = {};
#pragma unroll
      for (int ks = 0; ks < 2; ++ks) {
        int keyrow = nf * 16 + (l & 15);
        int cp = (ks * 4 + (l >> 4)) ^ (keyrow & 7);
        bf8 kf = *(const bf8*)&lK[keyrow * 64 + cp * 8];
        a = MFMA16(qf[ks], kf, a);
      }
      int key = kt * 64 + nf * 16 + (l & 15);
      bool valid = key < TSEQ;
#pragma unroll
      for (int q = 0; q < 4; q++) s[nf][q] = valid ? a[q] * 0.125f : -1e30f;
    }
    __builtin_amdgcn_s_setprio(0);

#pragma unroll
    for (int q = 0; q < 4; q++) {
      float rm = fmaxf(fmaxf(s[0][q], s[1][q]), fmaxf(s[2][q], s[3][q]));
#pragma unroll
      for (int mm = 1; mm < 16; mm <<= 1) rm = fmaxf(rm, __shfl_xor(rm, mm));
      float mnew = fmaxf(m_run[q], rm);
      float corr = __expf(m_run[q] - mnew);
      m_run[q] = mnew;
      float rs = 0.f;
#pragma unroll
      for (int nf = 0; nf < 4; nf++) {
        float pv = __expf(s[nf][q] - mnew);
        p[nf][q] = pv;
        rs += pv;
      }
#pragma unroll
      for (int mm = 1; mm < 16; mm <<= 1) rs += __shfl_xor(rs, mm);
      l_run[q] = l_run[q] * corr + rs;
#pragma unroll
      for (int df = 0; df < 4; df++) o_acc[df][q] *= corr;
    }
#pragma unroll
    for (int nf = 0; nf < 4; nf++)
#pragma unroll
      for (int q = 0; q < 4; q++) {
        int qr = (l >> 4) * 4 + q;
        int key = nf * 16 + (l & 15);
        int cp = (key >> 3) ^ (qr & 7);
        lP[w * 1024 + qr * 64 + cp * 8 + (key & 7)] = f2bf(p[nf][q]);
      }
    __syncthreads();

#pragma unroll
    for (int ks = 0; ks < 2; ++ks) {
      int qr = l & 15;
      int cp = (ks * 4 + (l >> 4)) ^ (qr & 7);
      bf8 pf = *(const bf8*)&lP[w * 1024 + qr * 64 + cp * 8];
      unsigned kq0 = (unsigned)(ks * 8 + (l >> 4) * 2);
      unsigned abase = lvb + kq0 * 512u + (unsigned)(l & 15) * 8u;
      s4v ra0, ra1, rb0, rb1, rc0, rc1, rd0, rd1;
      asm volatile("ds_read_b64_tr_b16 %0, %1" : "=v"(ra0) : "v"(abase));
      asm volatile("ds_read_b64_tr_b16 %0, %1" : "=v"(ra1) : "v"(abase + 512u));
      asm volatile("ds_read_b64_tr_b16 %0, %1" : "=v"(rb0) : "v"(abase + 128u));
      asm volatile("ds_read_b64_tr_b16 %0, %1" : "=v"(rb1) : "v"(abase + 640u));
      asm volatile("ds_read_b64_tr_b16 %0, %1" : "=v"(rc0) : "v"(abase + 256u));
      asm volatile("ds_read_b64_tr_b16 %0, %1" : "=v"(rc1) : "v"(abase + 768u));
      asm volatile("ds_read_b64_tr_b16 %0, %1" : "=v"(rd0) : "v"(abase + 384u));
      asm volatile("ds_read_b64_tr_b16 %0, %1" : "=v"(rd1) : "v"(abase + 896u));
      asm volatile("s_waitcnt lgkmcnt(0)" ::: "memory");
      __builtin_amdgcn_sched_barrier(0);
      bf8 vfa = __builtin_shufflevector(ra0, ra1, 0, 1, 2, 3, 4, 5, 6, 7);
      bf8 vfb = __builtin_shufflevector(rb0, rb1, 0, 1, 2, 3, 4, 5, 6, 7);
      bf8 vfc = __builtin_shufflevector(rc0, rc1, 0, 1, 2, 3, 4, 5, 6, 7);
      bf8 vfd = __builtin_shufflevector(rd0, rd1, 0, 1, 2, 3, 4, 5, 6, 7);
      __builtin_amdgcn_s_setprio(1);
      o_acc[0] = MFMA16(pf, vfa, o_acc[0]);
      o_acc[1] = MFMA16(pf, vfb, o_acc[1]);
      o_acc[2] = MFMA16(pf, vfc, o_acc[2]);
      o_acc[3] = MFMA16(pf, vfd, o_acc[3]);
      __builtin_amdgcn_s_setprio(0);
    }
  }
#pragma unroll
  for (int df = 0; df < 4; df++) {
#pragma unroll
    for (int q = 0; q < 4; q++) {
      int tq = m0 + w * 16 + (l >> 4) * 4 + q;
      if (tq < TSEQ) {
        float val = o_acc[df][q] / l_run[q];
        aout[(tokbase + tq) * DIMM + h * 64 + df * 16 + (l & 15)] = f2bf(val);
      }
    }
  }
}

// ---------------- launch ----------------
extern "C" void kernel_launch(void* const* d_in, const int* in_sizes, int n_in,
                              void* d_out, int out_size, void* d_ws, size_t ws_size,
                              hipStream_t stream) {
  const float* x      = (const float*)d_in[0];
  const float* ln1_g  = (const float*)d_in[1];
  const float* ln1_b  = (const float*)d_in[2];
  const float* qkv_w  = (const float*)d_in[3];
  const float* qkv_b  = (const float*)d_in[4];
  const float* proj_w = (const float*)d_in[5];
  const float* proj_b = (const float*)d_in[6];
  const float* ln2_g  = (const float*)d_in[7];
  const float* ln2_b  = (const float*)d_in[8];
  const float* fc1_w  = (const float*)d_in[9];
  const float* fc1_b  = (const float*)d_in[10];
  const float* fc2_w  = (const float*)d_in[11];
  const float* fc2_b  = (const float*)d_in[12];
  float* out = (float*)d_out;

  const size_t REQ = (size_t)(12582912 + (size_t)M_TOK * 1024 + (size_t)M_TOK * 3072) * 2;
  if (ws_size < REQ) return;

  short* w_qkv  = (short*)d_ws;                      // [3072][1024]
  short* w_proj = w_qkv + (size_t)3072 * 1024;       // [1024][1024]
  short* w_fc1  = w_proj + (size_t)1024 * 1024;      // [4096][1024]
  short* w_fc2  = w_fc1 + (size_t)4096 * 1024;       // [1024][4096]
  short* bufA   = w_fc2 + (size_t)1024 * 4096;       // [M][1024]
  short* bufB   = bufA + (size_t)M_TOK * 1024;       // [M][3072]

  dim3 blk(256);
  conv_t_kernel<<<dim3(3072 / 32, 1024 / 32), blk, 0, stream>>>(qkv_w, w_qkv, 1024, 3072);
  conv_t_kernel<<<dim3(1024 / 32, 1024 / 32), blk, 0, stream>>>(proj_w, w_proj, 1024, 1024);
  conv_t_kernel<<<dim3(4096 / 32, 1024 / 32), blk, 0, stream>>>(fc1_w, w_fc1, 1024, 4096);
  conv_t_kernel<<<dim3(1024 / 32, 4096 / 32), blk, 0, stream>>>(fc2_w, w_fc2, 4096, 1024);
  // LN1: x -> bufA
  ln_kernel<<<M_TOK, blk, 0, stream>>>(x, ln1_g, ln1_b, bufA);
  // QKV: bufA @ w_qkv^T -> bufB   (grid 145*24 = 3480)
  gemm_kernel<0><<<NTMK * 24, blk, 0, stream>>>(bufA, w_qkv, qkv_b, nullptr, bufB, nullptr,
                                                M_TOK, 1024, 3072, 1024, 1024, 24);
  // attention: bufB -> bufA
  attn_kernel<<<dim3(NBATCH * NH, 10), blk, 0, stream>>>(bufB, bufA);
  // proj + residual(x) -> out (x1)   (grid 1160)
  gemm_kernel<1><<<NTMK * 8, blk, 0, stream>>>(bufA, w_proj, proj_b, x, nullptr, out,
                                               M_TOK, 1024, 1024, 1024, 1024, 8);
  // LN2 on x1 -> bufA
  ln_kernel<<<M_TOK, blk, 0, stream>>>(out, ln2_g, ln2_b, bufA);
  // FFN in 2 hidden-dim chunks of 2048
  for (int c = 0; c < 2; ++c) {
    // FC1 chunk + GELU: bufA @ w_fc1[c*2048:+2048]^T -> bufB [M][2048]  (grid 2320)
    gemm_kernel<2><<<NTMK * 16, blk, 0, stream>>>(bufA, w_fc1 + (size_t)c * 2048 * 1024,
                                                  fc1_b + c * 2048, nullptr, bufB, nullptr,
                                                  M_TOK, 1024, 2048, 1024, 1024, 16);
    // FC2 chunk: out (+)= bufB @ w_fc2[:, c*2048:+2048]^T  (grid 1160)
    if (c == 0) {
      gemm_kernel<1><<<NTMK * 8, blk, 0, stream>>>(bufB, w_fc2 + (size_t)c * 2048, fc2_b,
                                                   out, nullptr, out, M_TOK, 2048, 1024,
                                                   2048, 4096, 8);
    } else {
      gemm_kernel<3><<<NTMK * 8, blk, 0, stream>>>(bufB, w_fc2 + (size_t)c * 2048, fc2_b,
                                                   out, nullptr, out, M_TOK, 2048, 1024,
                                                   2048, 4096, 8);
    }
  }
}